// Round 4
// baseline (1581.441 us; speedup 1.0000x reference)
//
#include <hip/hip_runtime.h>

// Causal self-attention fwd, B=2, H=16, S=2048, D=64.
// Inputs fp32 (dtype sniff kept as insurance). Outputs fp32:
// d_out = [out (B*H*S*D)] ++ [attention (B*H*S*S)].
//
// Round 4: occupancy. Same QB=4 tile algorithm as round 3 (measured: FETCH
// 33 MB = K/V read once; VALU 59%, stall 41%, 16 waves/CU cap), but 512
// threads/block -> 8 waves, VGPR ~68 allows ~28 waves/CU. Per-thread work
// halves; phase-head latencies (scalar Q reloads, VMEM, 4 barriers) overlap
// across 2x more resident waves. PV partials padded (17 float4 stride) to
// break the reduce-phase bank conflict.

#define B_ 2
#define H_ 16
#define S_ 2048
#define D_ 64
#define QB 4
#define NT 512
#define NW (NT/64)

typedef unsigned short u16;
typedef unsigned int   u32;
typedef float f32x4 __attribute__((ext_vector_type(4)));

__device__ __forceinline__ float bf2f(u16 h) {
    union { u32 u; float f; } x; x.u = ((u32)h) << 16; return x.f;
}

__device__ __forceinline__ float wred_max(float v) {
    #pragma unroll
    for (int o = 32; o > 0; o >>= 1) v = fmaxf(v, __shfl_xor(v, o, 64));
    return v;
}
__device__ __forceinline__ float wred_sum(float v) {
    #pragma unroll
    for (int o = 32; o > 0; o >>= 1) v += __shfl_xor(v, o, 64);
    return v;
}

__global__ __launch_bounds__(NT)
void attn_tile_kernel(const void* __restrict__ Qv, const void* __restrict__ Kv,
                      const void* __restrict__ Vv, const int* __restrict__ maskp,
                      float* __restrict__ out, float* __restrict__ att)
{
    const int tid = threadIdx.x;

    // XCD-aware swizzle (16384 blocks, 8 XCDs, bijective).
    const int bid0 = blockIdx.x;
    const int bid  = (bid0 & 7) * ((B_ * H_ * S_ / QB) >> 3) + (bid0 >> 3);

    const int bh = bid >> 9;               // 512 blocks per bh
    const int q0 = (bid & 511) << 2;
    const int causal = maskp[0];
    const int km0 = causal ? (q0 + 0) : (S_ - 1);
    const int km1 = causal ? (q0 + 1) : (S_ - 1);
    const int km2 = causal ? (q0 + 2) : (S_ - 1);
    const int km3 = causal ? (q0 + 3) : (S_ - 1);
    const int kmaxB = km3;                 // uniform block bound

    // sMem4: PV partials [QB][32 jg][17 float4 pad] = 34816 B.
    // First QB*S_ floats (32768 B) alias as the score/e rows sS.
    __shared__ float4 sMem4[QB * 32 * 17];
    float* sS = reinterpret_cast<float*>(sMem4);
    __shared__ float sMaxP[NW * QB];
    __shared__ float sSumP[NW * QB];
    __shared__ float sInv[QB];

    const size_t base = (size_t)bh * S_ * D_;
    const int lane = tid & 63;
    const int wid  = tid >> 6;

    // ---- dtype sniff (wave-parallel, uniform result) ----
    bool isf32;
    {
        u32 w = ((const u32*)Qv)[lane];
        int e0 = (int)((w >> 7)  & 0xFFu);
        int e1 = (int)((w >> 23) & 0xFFu);
        unsigned long long b = __ballot(e0 >= 0x8F || e1 >= 0x8F);
        isf32 = (__popcll(b) >= 4);
    }

    // ---- scores: sS[qq][j] = Q[q0+qq].K[j] (unscaled; /8 folded into exp),
    // masked cells -inf. Q via block-uniform pointer (scalar loads); each K
    // row loaded once, dotted with 4 Q rows. Thread j-slots: j == tid mod NT.
    float lm0 = -INFINITY, lm1 = -INFINITY, lm2 = -INFINITY, lm3 = -INFINITY;
    if (isf32) {
        const float4* Q4u = reinterpret_cast<const float4*>(
            (const float*)Qv + base + (size_t)q0 * D_);       // uniform
        const float4* K4 = reinterpret_cast<const float4*>((const float*)Kv + base);
        int off = 0;
        for (; off + (NT - 1) <= kmaxB; off += NT) {          // full tiles
            const int j = off + tid;
            const float4* kr = K4 + (size_t)j * 16;
            float4 kq[16];
            #pragma unroll
            for (int c = 0; c < 16; ++c) kq[c] = kr[c];
            float d0 = 0.f, d1 = 0.f, d2 = 0.f, d3 = 0.f;
            #pragma unroll
            for (int c = 0; c < 16; ++c) {
                float4 a0 = Q4u[c], a1 = Q4u[16 + c], a2 = Q4u[32 + c], a3 = Q4u[48 + c];
                d0 += a0.x*kq[c].x + a0.y*kq[c].y + a0.z*kq[c].z + a0.w*kq[c].w;
                d1 += a1.x*kq[c].x + a1.y*kq[c].y + a1.z*kq[c].z + a1.w*kq[c].w;
                d2 += a2.x*kq[c].x + a2.y*kq[c].y + a2.z*kq[c].z + a2.w*kq[c].w;
                d3 += a3.x*kq[c].x + a3.y*kq[c].y + a3.z*kq[c].z + a3.w*kq[c].w;
            }
            float s0 = (j <= km0) ? d0 : -INFINITY;
            float s1 = (j <= km1) ? d1 : -INFINITY;
            float s2 = (j <= km2) ? d2 : -INFINITY;
            float s3 = (j <= km3) ? d3 : -INFINITY;
            sS[0*S_ + j] = s0; lm0 = fmaxf(lm0, s0);
            sS[1*S_ + j] = s1; lm1 = fmaxf(lm1, s1);
            sS[2*S_ + j] = s2; lm2 = fmaxf(lm2, s2);
            sS[3*S_ + j] = s3; lm3 = fmaxf(lm3, s3);
        }
        {   // tail tile (guarded)
            const int j = off + tid;
            if (j <= kmaxB) {
                const float4* kr = K4 + (size_t)j * 16;
                float d0 = 0.f, d1 = 0.f, d2 = 0.f, d3 = 0.f;
                #pragma unroll
                for (int c = 0; c < 16; ++c) {
                    float4 kc = kr[c];
                    float4 a0 = Q4u[c], a1 = Q4u[16 + c], a2 = Q4u[32 + c], a3 = Q4u[48 + c];
                    d0 += a0.x*kc.x + a0.y*kc.y + a0.z*kc.z + a0.w*kc.w;
                    d1 += a1.x*kc.x + a1.y*kc.y + a1.z*kc.z + a1.w*kc.w;
                    d2 += a2.x*kc.x + a2.y*kc.y + a2.z*kc.z + a2.w*kc.w;
                    d3 += a3.x*kc.x + a3.y*kc.y + a3.z*kc.z + a3.w*kc.w;
                }
                float s0 = (j <= km0) ? d0 : -INFINITY;
                float s1 = (j <= km1) ? d1 : -INFINITY;
                float s2 = (j <= km2) ? d2 : -INFINITY;
                float s3 = (j <= km3) ? d3 : -INFINITY;
                sS[0*S_ + j] = s0; lm0 = fmaxf(lm0, s0);
                sS[1*S_ + j] = s1; lm1 = fmaxf(lm1, s1);
                sS[2*S_ + j] = s2; lm2 = fmaxf(lm2, s2);
                sS[3*S_ + j] = s3; lm3 = fmaxf(lm3, s3);
            }
        }
    } else {
        const u16* Qh = (const u16*)Qv + base + (size_t)q0 * D_;   // uniform
        const u16* Kh = (const u16*)Kv + base;
        for (int off = 0; off <= kmaxB; off += NT) {
            const int j = off + tid;
            if (j <= kmaxB) {
                const u16* kr = Kh + (size_t)j * D_;
                float d0 = 0.f, d1 = 0.f, d2 = 0.f, d3 = 0.f;
                #pragma unroll
                for (int c = 0; c < D_; ++c) {
                    float kc = bf2f(kr[c]);
                    d0 += bf2f(Qh[c])       * kc;
                    d1 += bf2f(Qh[64 + c])  * kc;
                    d2 += bf2f(Qh[128 + c]) * kc;
                    d3 += bf2f(Qh[192 + c]) * kc;
                }
                float s0 = (j <= km0) ? d0 : -INFINITY;
                float s1 = (j <= km1) ? d1 : -INFINITY;
                float s2 = (j <= km2) ? d2 : -INFINITY;
                float s3 = (j <= km3) ? d3 : -INFINITY;
                sS[0*S_ + j] = s0; lm0 = fmaxf(lm0, s0);
                sS[1*S_ + j] = s1; lm1 = fmaxf(lm1, s1);
                sS[2*S_ + j] = s2; lm2 = fmaxf(lm2, s2);
                sS[3*S_ + j] = s3; lm3 = fmaxf(lm3, s3);
            }
        }
    }

    // ---- block max per row (barrier 1) ----
    lm0 = wred_max(lm0); lm1 = wred_max(lm1);
    lm2 = wred_max(lm2); lm3 = wred_max(lm3);
    if (lane == 0) {
        sMaxP[wid*QB + 0] = lm0; sMaxP[wid*QB + 1] = lm1;
        sMaxP[wid*QB + 2] = lm2; sMaxP[wid*QB + 3] = lm3;
    }
    __syncthreads();
    float m0 = -INFINITY, m1 = -INFINITY, m2 = -INFINITY, m3 = -INFINITY;
    #pragma unroll
    for (int w = 0; w < NW; ++w) {
        m0 = fmaxf(m0, sMaxP[w*QB + 0]);
        m1 = fmaxf(m1, sMaxP[w*QB + 1]);
        m2 = fmaxf(m2, sMaxP[w*QB + 2]);
        m3 = fmaxf(m3, sMaxP[w*QB + 3]);
    }

    // ---- e = exp((s-m)/8) in place (own slots); masked (-inf) -> 0 ----
    float ls0 = 0.f, ls1 = 0.f, ls2 = 0.f, ls3 = 0.f;
    for (int j = tid; j <= kmaxB; j += NT) {
        float e0 = __expf((sS[0*S_ + j] - m0) * 0.125f);
        float e1 = __expf((sS[1*S_ + j] - m1) * 0.125f);
        float e2 = __expf((sS[2*S_ + j] - m2) * 0.125f);
        float e3 = __expf((sS[3*S_ + j] - m3) * 0.125f);
        sS[0*S_ + j] = e0; ls0 += e0;
        sS[1*S_ + j] = e1; ls1 += e1;
        sS[2*S_ + j] = e2; ls2 += e2;
        sS[3*S_ + j] = e3; ls3 += e3;
    }
    ls0 = wred_sum(ls0); ls1 = wred_sum(ls1);
    ls2 = wred_sum(ls2); ls3 = wred_sum(ls3);
    if (lane == 0) {
        sSumP[wid*QB + 0] = ls0; sSumP[wid*QB + 1] = ls1;
        sSumP[wid*QB + 2] = ls2; sSumP[wid*QB + 3] = ls3;
    }
    __syncthreads();                       // barrier 2: publishes e rows too
    float t0 = 0.f, t1 = 0.f, t2 = 0.f, t3 = 0.f;
    #pragma unroll
    for (int w = 0; w < NW; ++w) {
        t0 += sSumP[w*QB + 0]; t1 += sSumP[w*QB + 1];
        t2 += sSumP[w*QB + 2]; t3 += sSumP[w*QB + 3];
    }
    const float inv0 = 1.f / t0, inv1 = 1.f / t1;
    const float inv2 = 1.f / t2, inv3 = 1.f / t3;
    if (tid == 0) { sInv[0] = inv0; sInv[1] = inv1; sInv[2] = inv2; sInv[3] = inv3; }

    // ---- attention rows: p = e*inv for j<=kmaxB else 0; nt stores.
    // (rows' causal tails inside kmaxB are already exactly 0 from exp(-inf))
    {
        const int j0 = tid * 4;            // 512 * 4 == 2048
        const size_t arow = ((size_t)bh * S_ + q0) * S_;
        #define ATT_WRITE(QQ, INVQ)                                            \
        {                                                                      \
            const float4* s4 = reinterpret_cast<const float4*>(sS + QQ*S_);    \
            float4 v0 = s4[tid];                                               \
            f32x4 p0;                                                          \
            p0.x = (j0+0 <= kmaxB) ? v0.x*INVQ : 0.f;                          \
            p0.y = (j0+1 <= kmaxB) ? v0.y*INVQ : 0.f;                          \
            p0.z = (j0+2 <= kmaxB) ? v0.z*INVQ : 0.f;                          \
            p0.w = (j0+3 <= kmaxB) ? v0.w*INVQ : 0.f;                          \
            f32x4* a4 = reinterpret_cast<f32x4*>(att + arow + (size_t)QQ*S_ + j0); \
            __builtin_nontemporal_store(p0, a4);                               \
        }
        ATT_WRITE(0, inv0) ATT_WRITE(1, inv1) ATT_WRITE(2, inv2) ATT_WRITE(3, inv3)
        #undef ATT_WRITE
    }

    // ---- PV: acc[qq] += e[qq][j] * V[j][dq]; 32 j-groups x 16 d-quads ----
    const int dq = tid & 15;
    const int jg = tid >> 4;               // 0..31
    float4 acc0 = make_float4(0.f,0.f,0.f,0.f);
    float4 acc1 = acc0, acc2 = acc0, acc3 = acc0;
    if (isf32) {
        const float4* V4 = reinterpret_cast<const float4*>((const float*)Vv + base);
        const float4* vp = V4 + (size_t)jg * 16 + dq;
        #pragma unroll 4
        for (int j = jg; j <= kmaxB; j += 32, vp += 512) {
            float4 v0 = vp[0];
            float p0 = sS[0*S_ + j], p1 = sS[1*S_ + j];
            float p2 = sS[2*S_ + j], p3 = sS[3*S_ + j];
            acc0.x = fmaf(p0, v0.x, acc0.x); acc0.y = fmaf(p0, v0.y, acc0.y);
            acc0.z = fmaf(p0, v0.z, acc0.z); acc0.w = fmaf(p0, v0.w, acc0.w);
            acc1.x = fmaf(p1, v0.x, acc1.x); acc1.y = fmaf(p1, v0.y, acc1.y);
            acc1.z = fmaf(p1, v0.z, acc1.z); acc1.w = fmaf(p1, v0.w, acc1.w);
            acc2.x = fmaf(p2, v0.x, acc2.x); acc2.y = fmaf(p2, v0.y, acc2.y);
            acc2.z = fmaf(p2, v0.z, acc2.z); acc2.w = fmaf(p2, v0.w, acc2.w);
            acc3.x = fmaf(p3, v0.x, acc3.x); acc3.y = fmaf(p3, v0.y, acc3.y);
            acc3.z = fmaf(p3, v0.z, acc3.z); acc3.w = fmaf(p3, v0.w, acc3.w);
        }
    } else {
        const u16* Vh = (const u16*)Vv + base;
        for (int j = jg; j <= kmaxB; j += 32) {
            ushort4 h = reinterpret_cast<const ushort4*>(Vh + (size_t)j * D_)[dq];
            float vx = bf2f(h.x), vy = bf2f(h.y), vz = bf2f(h.z), vw = bf2f(h.w);
            float p0 = sS[0*S_ + j], p1 = sS[1*S_ + j];
            float p2 = sS[2*S_ + j], p3 = sS[3*S_ + j];
            acc0.x = fmaf(p0, vx, acc0.x); acc0.y = fmaf(p0, vy, acc0.y);
            acc0.z = fmaf(p0, vz, acc0.z); acc0.w = fmaf(p0, vw, acc0.w);
            acc1.x = fmaf(p1, vx, acc1.x); acc1.y = fmaf(p1, vy, acc1.y);
            acc1.z = fmaf(p1, vz, acc1.z); acc1.w = fmaf(p1, vw, acc1.w);
            acc2.x = fmaf(p2, vx, acc2.x); acc2.y = fmaf(p2, vy, acc2.y);
            acc2.z = fmaf(p2, vz, acc2.z); acc2.w = fmaf(p2, vw, acc2.w);
            acc3.x = fmaf(p3, vx, acc3.x); acc3.y = fmaf(p3, vy, acc3.y);
            acc3.z = fmaf(p3, vz, acc3.z); acc3.w = fmaf(p3, vw, acc3.w);
        }
    }

    // ---- partials into padded sMem4 (aliases sS; all reads done) ----
    __syncthreads();                       // barrier 3
    sMem4[(0*32 + jg)*17 + dq] = acc0;
    sMem4[(1*32 + jg)*17 + dq] = acc1;
    sMem4[(2*32 + jg)*17 + dq] = acc2;
    sMem4[(3*32 + jg)*17 + dq] = acc3;
    __syncthreads();                       // barrier 4
    if (tid < QB * D_) {                   // 256 outputs
        const int qq = tid >> 6;
        const int d  = tid & 63;
        const float* sp = reinterpret_cast<const float*>(sMem4);
        float o = 0.f;
        #pragma unroll
        for (int g = 0; g < 32; ++g) o += sp[68*(qq*32 + g) + d];
        out[((size_t)bh * S_ + q0 + qq) * D_ + d] = o * sInv[qq];
    }
}

extern "C" void kernel_launch(void* const* d_in, const int* in_sizes, int n_in,
                              void* d_out, int out_size, void* d_ws, size_t ws_size,
                              hipStream_t stream) {
    const void* Q = d_in[0];
    const void* K = d_in[1];
    const void* V = d_in[2];
    const int* mask = (const int*)d_in[3];

    float* out = (float*)d_out;                              // B*H*S*D floats
    float* att = out + (size_t)B_ * H_ * S_ * D_;            // B*H*S*S floats

    const int nblk = (B_ * H_ * S_) / QB;                    // 16384 blocks
    attn_tile_kernel<<<nblk, NT, 0, stream>>>(Q, K, V, mask, out, att);
}

// Round 5
// 995.369 us; speedup vs baseline: 1.5888x; 1.5888x over previous
//
#include <hip/hip_runtime.h>

// Causal self-attention fwd, B=2, H=16, S=2048, D=64.
// Inputs fp32 (dtype sniff kept as insurance). Outputs fp32:
// d_out = [out (B*H*S*D)] ++ [attention (B*H*S*S)].
//
// Round 5: QB=8 at NT=256 (round-4's NT=512 regressed: occupancy fell to
// ~1 block/CU and 512-wide j-tiles waste ~25% issue on the causal tail).
// QB=8 halves L2-side K/V traffic vs round-3 (8.4 -> 4.2 GB/dispatch) and
// halves VMEM instruction count; each K row feeds 8 dots, each V quad 8 accs.
// LDS: 64 KB score rows (2 blocks/CU, 8 waves); PV partials (17-stride pad)
// alias the score region after a barrier. All LDS passes use float4 at
// tid*4 stride (optimal 8-per-quad-bank pattern); PV p-reads are wave
// broadcasts. kmaxB == 7 mod 8 for both mask values -> quad guards uniform.

#define B_ 2
#define H_ 16
#define S_ 2048
#define D_ 64
#define QB 8
#define NT 256

typedef unsigned short u16;
typedef unsigned int   u32;
typedef float f32x4 __attribute__((ext_vector_type(4)));

__device__ __forceinline__ float bf2f(u16 h) {
    union { u32 u; float f; } x; x.u = ((u32)h) << 16; return x.f;
}
__device__ __forceinline__ float wred_max(float v) {
    #pragma unroll
    for (int o = 32; o > 0; o >>= 1) v = fmaxf(v, __shfl_xor(v, o, 64));
    return v;
}
__device__ __forceinline__ float wred_sum(float v) {
    #pragma unroll
    for (int o = 32; o > 0; o >>= 1) v += __shfl_xor(v, o, 64);
    return v;
}

__global__ __launch_bounds__(NT)
void attn_tile8_kernel(const void* __restrict__ Qv, const void* __restrict__ Kv,
                       const void* __restrict__ Vv, const int* __restrict__ maskp,
                       float* __restrict__ out, float* __restrict__ att)
{
    const int tid = threadIdx.x;

    // XCD swizzle: 8192 blocks, 1024-block contiguous chunk per XCD
    // (= 4 heads' K/V = 4 MB = one L2). Bijective since 8192 % 8 == 0.
    const int bid0 = blockIdx.x;
    const int bid  = (bid0 & 7) * 1024 + (bid0 >> 3);

    const int bh = bid >> 8;               // 256 blocks per bh
    const int q0 = (bid & 255) << 3;       // first of 8 q rows
    const int causal = maskp[0];
    const int kmaxB = causal ? (q0 + QB - 1) : (S_ - 1);   // == 7 mod 8

    __shared__ float sS[QB * S_];          // 64 KB: score rows -> e rows
    __shared__ float sMaxP[4 * QB];
    __shared__ float sSumP[4 * QB];
    __shared__ float sInv[QB];

    const size_t base = (size_t)bh * S_ * D_;
    const int lane = tid & 63;
    const int wid  = tid >> 6;

    // ---- dtype sniff (wave-parallel, uniform result) ----
    bool isf32;
    {
        u32 w = ((const u32*)Qv)[lane];
        int e0 = (int)((w >> 7)  & 0xFFu);
        int e1 = (int)((w >> 23) & 0xFFu);
        unsigned long long b = __ballot(e0 >= 0x8F || e1 >= 0x8F);
        isf32 = (__popcll(b) >= 4);
    }

    int km[QB];
    #pragma unroll
    for (int r = 0; r < QB; ++r) km[r] = causal ? (q0 + r) : (S_ - 1);

    // ---- scores: sS[r][j] = Q[q0+r].K[j] (unscaled; /8 folded into exp),
    // masked cells -inf. Q via block-uniform pointer (scalar loads, scalar
    // cache); each K row loaded once into regs, dotted with all 8 Q rows.
    float lm[QB];
    #pragma unroll
    for (int r = 0; r < QB; ++r) lm[r] = -INFINITY;

    if (isf32) {
        const float4* Q4u = reinterpret_cast<const float4*>(
            (const float*)Qv + base + (size_t)q0 * D_);       // uniform
        const float4* K4 = reinterpret_cast<const float4*>((const float*)Kv + base);
        for (int off = 0; off <= kmaxB; off += NT) {
            const int j = off + tid;
            if (j <= kmaxB) {
                const float4* kr = K4 + (size_t)j * 16;
                float4 kq[16];
                #pragma unroll
                for (int c = 0; c < 16; ++c) kq[c] = kr[c];
                float dd[QB];
                #pragma unroll
                for (int r = 0; r < QB; ++r) dd[r] = 0.f;
                #pragma unroll
                for (int c = 0; c < 16; ++c) {
                    #pragma unroll
                    for (int r = 0; r < QB; ++r) {
                        float4 a = Q4u[r * 16 + c];
                        dd[r] += a.x*kq[c].x + a.y*kq[c].y + a.z*kq[c].z + a.w*kq[c].w;
                    }
                }
                #pragma unroll
                for (int r = 0; r < QB; ++r) {
                    float s = (j <= km[r]) ? dd[r] : -INFINITY;
                    sS[r * S_ + j] = s;
                    lm[r] = fmaxf(lm[r], s);
                }
            }
        }
    } else {
        const u16* Qh = (const u16*)Qv + base + (size_t)q0 * D_;   // uniform
        const u16* Kh = (const u16*)Kv + base;
        for (int off = 0; off <= kmaxB; off += NT) {
            const int j = off + tid;
            if (j <= kmaxB) {
                const u16* kr = Kh + (size_t)j * D_;
                float dd[QB];
                #pragma unroll
                for (int r = 0; r < QB; ++r) dd[r] = 0.f;
                #pragma unroll
                for (int c = 0; c < D_; ++c) {
                    float kc = bf2f(kr[c]);
                    #pragma unroll
                    for (int r = 0; r < QB; ++r) dd[r] += bf2f(Qh[r * D_ + c]) * kc;
                }
                #pragma unroll
                for (int r = 0; r < QB; ++r) {
                    float s = (j <= km[r]) ? dd[r] : -INFINITY;
                    sS[r * S_ + j] = s;
                    lm[r] = fmaxf(lm[r], s);
                }
            }
        }
    }

    // ---- block max per row (barrier 1) ----
    #pragma unroll
    for (int r = 0; r < QB; ++r) lm[r] = wred_max(lm[r]);
    if (lane == 0) {
        #pragma unroll
        for (int r = 0; r < QB; ++r) sMaxP[wid * QB + r] = lm[r];
    }
    __syncthreads();
    float m[QB];
    #pragma unroll
    for (int r = 0; r < QB; ++r)
        m[r] = fmaxf(fmaxf(sMaxP[r], sMaxP[QB + r]),
                     fmaxf(sMaxP[2*QB + r], sMaxP[3*QB + r]));

    // ---- e = exp((s-m)/8) in place, float4 at tid*4 stride; sum per row ----
    float ls[QB];
    #pragma unroll
    for (int r = 0; r < QB; ++r) ls[r] = 0.f;
    for (int off = 0; off < S_; off += NT * 4) {
        const int j0e = off + tid * 4;
        if (j0e <= kmaxB) {                // kmaxB == 3 mod 4 -> quad uniform
            #pragma unroll
            for (int r = 0; r < QB; ++r) {
                float4 sv = *reinterpret_cast<float4*>(sS + r * S_ + j0e);
                float e0 = __expf((sv.x - m[r]) * 0.125f);
                float e1 = __expf((sv.y - m[r]) * 0.125f);
                float e2 = __expf((sv.z - m[r]) * 0.125f);
                float e3 = __expf((sv.w - m[r]) * 0.125f);
                *reinterpret_cast<float4*>(sS + r * S_ + j0e) =
                    make_float4(e0, e1, e2, e3);
                ls[r] += (e0 + e1) + (e2 + e3);
            }
        }
    }
    #pragma unroll
    for (int r = 0; r < QB; ++r) ls[r] = wred_sum(ls[r]);
    if (lane == 0) {
        #pragma unroll
        for (int r = 0; r < QB; ++r) sSumP[wid * QB + r] = ls[r];
    }
    __syncthreads();                       // barrier 2: publishes e rows too
    float inv[QB];
    #pragma unroll
    for (int r = 0; r < QB; ++r)
        inv[r] = 1.f / ((sSumP[r] + sSumP[QB + r]) +
                        (sSumP[2*QB + r] + sSumP[3*QB + r]));
    if (tid == 0) {
        #pragma unroll
        for (int r = 0; r < QB; ++r) sInv[r] = inv[r];
    }

    // ---- attention rows: p = e*inv for j<=kmaxB else 0; nt stores.
    // (in-row causal zeros already exact from exp(-inf)=0)
    {
        const size_t arow = ((size_t)bh * S_ + q0) * S_;
        for (int off = 0; off < S_; off += NT * 4) {
            const int j0a = off + tid * 4;
            const bool wr = (j0a <= kmaxB);
            #pragma unroll
            for (int r = 0; r < QB; ++r) {
                f32x4 p;
                if (wr) {
                    float4 v = *reinterpret_cast<const float4*>(sS + r * S_ + j0a);
                    p.x = v.x * inv[r]; p.y = v.y * inv[r];
                    p.z = v.z * inv[r]; p.w = v.w * inv[r];
                } else {
                    p.x = 0.f; p.y = 0.f; p.z = 0.f; p.w = 0.f;
                }
                f32x4* a4 = reinterpret_cast<f32x4*>(att + arow + (size_t)r * S_ + j0a);
                __builtin_nontemporal_store(p, a4);
            }
        }
    }

    // ---- PV: acc[r] += e[r][j] * V[j][dq]; 4-consecutive-j blocks.
    // V: 4x float4 global; P: 8x ds_read_b128 broadcast (conflict-free).
    const int dq = tid & 15;
    const int jg = tid >> 4;               // 0..15
    float4 acc[QB];
    #pragma unroll
    for (int r = 0; r < QB; ++r) acc[r] = make_float4(0.f, 0.f, 0.f, 0.f);

    if (isf32) {
        const float4* V4 = reinterpret_cast<const float4*>((const float*)Vv + base);
        for (int j0p = 4 * jg; j0p <= kmaxB; j0p += 64) {  // kmaxB==3 mod 4
            float4 v0 = V4[(size_t)(j0p + 0) * 16 + dq];
            float4 v1 = V4[(size_t)(j0p + 1) * 16 + dq];
            float4 v2 = V4[(size_t)(j0p + 2) * 16 + dq];
            float4 v3 = V4[(size_t)(j0p + 3) * 16 + dq];
            #pragma unroll
            for (int r = 0; r < QB; ++r) {
                float4 p = *reinterpret_cast<const float4*>(sS + r * S_ + j0p);
                acc[r].x = fmaf(p.x, v0.x, acc[r].x); acc[r].y = fmaf(p.x, v0.y, acc[r].y);
                acc[r].z = fmaf(p.x, v0.z, acc[r].z); acc[r].w = fmaf(p.x, v0.w, acc[r].w);
                acc[r].x = fmaf(p.y, v1.x, acc[r].x); acc[r].y = fmaf(p.y, v1.y, acc[r].y);
                acc[r].z = fmaf(p.y, v1.z, acc[r].z); acc[r].w = fmaf(p.y, v1.w, acc[r].w);
                acc[r].x = fmaf(p.z, v2.x, acc[r].x); acc[r].y = fmaf(p.z, v2.y, acc[r].y);
                acc[r].z = fmaf(p.z, v2.z, acc[r].z); acc[r].w = fmaf(p.z, v2.w, acc[r].w);
                acc[r].x = fmaf(p.w, v3.x, acc[r].x); acc[r].y = fmaf(p.w, v3.y, acc[r].y);
                acc[r].z = fmaf(p.w, v3.z, acc[r].z); acc[r].w = fmaf(p.w, v3.w, acc[r].w);
            }
        }
    } else {
        const u16* Vh = (const u16*)Vv + base;
        for (int j0p = 4 * jg; j0p <= kmaxB; j0p += 64) {
            ushort4 h0 = reinterpret_cast<const ushort4*>(Vh + (size_t)(j0p + 0) * D_)[dq];
            ushort4 h1 = reinterpret_cast<const ushort4*>(Vh + (size_t)(j0p + 1) * D_)[dq];
            ushort4 h2 = reinterpret_cast<const ushort4*>(Vh + (size_t)(j0p + 2) * D_)[dq];
            ushort4 h3 = reinterpret_cast<const ushort4*>(Vh + (size_t)(j0p + 3) * D_)[dq];
            float4 v0 = make_float4(bf2f(h0.x), bf2f(h0.y), bf2f(h0.z), bf2f(h0.w));
            float4 v1 = make_float4(bf2f(h1.x), bf2f(h1.y), bf2f(h1.z), bf2f(h1.w));
            float4 v2 = make_float4(bf2f(h2.x), bf2f(h2.y), bf2f(h2.z), bf2f(h2.w));
            float4 v3 = make_float4(bf2f(h3.x), bf2f(h3.y), bf2f(h3.z), bf2f(h3.w));
            #pragma unroll
            for (int r = 0; r < QB; ++r) {
                float4 p = *reinterpret_cast<const float4*>(sS + r * S_ + j0p);
                acc[r].x = fmaf(p.x, v0.x, acc[r].x); acc[r].y = fmaf(p.x, v0.y, acc[r].y);
                acc[r].z = fmaf(p.x, v0.z, acc[r].z); acc[r].w = fmaf(p.x, v0.w, acc[r].w);
                acc[r].x = fmaf(p.y, v1.x, acc[r].x); acc[r].y = fmaf(p.y, v1.y, acc[r].y);
                acc[r].z = fmaf(p.y, v1.z, acc[r].z); acc[r].w = fmaf(p.y, v1.w, acc[r].w);
                acc[r].x = fmaf(p.z, v2.x, acc[r].x); acc[r].y = fmaf(p.z, v2.y, acc[r].y);
                acc[r].z = fmaf(p.z, v2.z, acc[r].z); acc[r].w = fmaf(p.z, v2.w, acc[r].w);
                acc[r].x = fmaf(p.w, v3.x, acc[r].x); acc[r].y = fmaf(p.w, v3.y, acc[r].y);
                acc[r].z = fmaf(p.w, v3.z, acc[r].z); acc[r].w = fmaf(p.w, v3.w, acc[r].w);
            }
        }
    }

    // ---- partials aliased over sS (17-float4 stride: optimal quad spread) ----
    __syncthreads();                       // barrier 3: all sS reads done
    float4* sPart4 = reinterpret_cast<float4*>(sS);   // [r][jg] stride 17
    #pragma unroll
    for (int r = 0; r < QB; ++r) sPart4[(r * 16 + jg) * 17 + dq] = acc[r];
    __syncthreads();                       // barrier 4
    {
        const float* spf = sS;
        for (int oo = tid; oo < QB * D_; oo += NT) {   // 512 outputs, 2/thread
            const int r = oo >> 6;
            const int d = oo & 63;
            float o = 0.f;
            #pragma unroll
            for (int g = 0; g < 16; ++g) o += spf[(r * 16 + g) * 68 + d];
            out[((size_t)bh * S_ + q0 + r) * D_ + d] = o * sInv[r];
        }
    }
}

extern "C" void kernel_launch(void* const* d_in, const int* in_sizes, int n_in,
                              void* d_out, int out_size, void* d_ws, size_t ws_size,
                              hipStream_t stream) {
    const void* Q = d_in[0];
    const void* K = d_in[1];
    const void* V = d_in[2];
    const int* mask = (const int*)d_in[3];

    float* out = (float*)d_out;                              // B*H*S*D floats
    float* att = out + (size_t)B_ * H_ * S_ * D_;            // B*H*S*S floats

    const int nblk = (B_ * H_ * S_) / QB;                    // 8192 blocks
    attn_tile8_kernel<<<nblk, NT, 0, stream>>>(Q, K, V, mask, out, att);
}